// Round 1
// 210.553 us; speedup vs baseline: 1.0011x; 1.0011x over previous
//
#include <hip/hip_runtime.h>

// STDP learner: tr_pre/tr_post elementwise + delta_w = 0.5*w*(conv-wgrad pair).
// delta_w[o,i,kh,kw] = 0.5*w[o,i,kh,kw] *
//   sum_{b,p,q} tpre[b,i,p+kh,q+kw]*out[b,o,p,q] - tpost[b,o,p,q]*in[b,i,p+kh,q+kw]
// Sizes: B=16 CIN=64 H=W=66 COUT=128 HO=WO=64 KH=KW=3
// out layout: [tr_pre 4460544][tr_post 8388608][delta_w 73728]
//
// R6: k_fill rewrite (was top dispatch: 63.4us @ 2.5 TB/s HBM, VALU 4% --
// issue/pattern-bound, not BW-bound):
//  - Part A (1280 blocks, grid-stride): flat float4 elementwise over N_POST.
//    Every instruction 100% lane-dense (old code: 8 contiguous floats/thread
//    -> 32B-stride lanes -> 25-50% density per instruction).
//  - Part B (768 blocks): wave-per-row, lanes 0..32 x float2. Dense 264B
//    loads/stores; bf16 pairs packed to dense 4B stores into 72-padded rows.
//    Pad cols 66..71 left garbage -- k_mfma's fb reads max col 65 (verified).
//  - 2048 total blocks w/ grid-stride (was 6472 tiny blocks, dispatch ramp).
// k_mfma / k_finalize unchanged this round (R5 structure).

typedef unsigned short ushort_t;
typedef unsigned int uint_t;
typedef __attribute__((ext_vector_type(8))) short short8;
typedef __attribute__((ext_vector_type(4))) float floatx4;
typedef __attribute__((ext_vector_type(2))) float floatx2;
typedef __attribute__((ext_vector_type(4))) int intx4;
typedef __attribute__((ext_vector_type(2))) unsigned int uintx2;

#define N_PRE   4460544      // 16*64*66*66
#define N_POST  8388608      // 16*128*64*64
#define N_DW    73728        // 128*64*9
#define O_TRPOST 4460544
#define O_DW     12849152
#define BROWS   67584        // (b*64+i)*66+h rows
#define BRAW    4866048      // 67584 * 72 elems per raw-B mat

#define FILL_A_BLOCKS 1280
#define FILL_B_BLOCKS 768
#define FILL_BLOCKS   2048
#define B_ROWS_PER_WAVE 22   // 768*4*22 = 67584 exactly

// async global->LDS, 16B/lane; LDS dst = wave-uniform base + lane*16
#define GLDS16(g, l) __builtin_amdgcn_global_load_lds( \
    (const __attribute__((address_space(1))) void*)(g), \
    (__attribute__((address_space(3))) void*)(l), 16, 0, 0)

__device__ __forceinline__ ushort_t f2bf(float f) {
  uint_t u = __builtin_bit_cast(uint_t, f);
  u = (u + 0x7FFFu + ((u >> 16) & 1u)) >> 16;   // RNE
  return (ushort_t)u;
}

__device__ __forceinline__ uint_t pk2bf(float a, float b) {
  return (uint_t)f2bf(a) | ((uint_t)f2bf(b) << 16);
}

// bytes [2..5] of (hi:lo) -- one v_alignbit_b32
__device__ __forceinline__ int bsh2(int hi, int lo) {
  return (int)((((unsigned long long)(uint_t)hi << 32) | (uint_t)lo) >> 16);
}

// ---- fused fill ------------------------------------------------------------
// blocks [0..1280): flat tr_post + A1/A2 bf16, float4 grid-stride (dense)
// blocks [1280..2048): wave-per-row tr_pre + raw bf16 B rows (72-elem stride)
__global__ __launch_bounds__(256)
void k_fill(const float* __restrict__ in_sp, const float* __restrict__ out_sp,
            const float* __restrict__ tpre, const float* __restrict__ tpost,
            float* __restrict__ o_trpre, float* __restrict__ o_trpost,
            ushort_t* __restrict__ A1, ushort_t* __restrict__ A2,
            ushort_t* __restrict__ B1, ushort_t* __restrict__ B2, int use_ws) {
  const int bx = blockIdx.x;
  if (bx < FILL_A_BLOCKS) {
    // ---- Part A: elementwise over N_POST, float4 granularity, dense lanes
    const int n4 = N_POST / 4;                         // 2097152
    const int stride = FILL_A_BLOCKS * 256;            // 327680
    for (int i4 = bx * 256 + (int)threadIdx.x; i4 < n4; i4 += stride) {
      floatx4 o = *(const floatx4*)(out_sp + i4 * 4);
      floatx4 p = *(const floatx4*)(tpost + i4 * 4);
      *(floatx4*)(o_trpost + i4 * 4) = 0.5f * p + o;
      if (use_ws) {
        uintx2 va = { pk2bf(o.x, o.y), pk2bf(o.z, o.w) };
        uintx2 vn = { pk2bf(-p.x, -p.y), pk2bf(-p.z, -p.w) };
        *(uintx2*)(A1 + i4 * 4) = va;                  // 8B dense
        *(uintx2*)(A2 + i4 * 4) = vn;
      }
    }
  } else {
    // ---- Part B: one wave per 66-col row; lanes 0..32 own float2 each
    const int l = threadIdx.x & 63;
    if (l >= 33) return;                               // no barriers: safe
    const int wid = (bx - FILL_A_BLOCKS) * 4 + ((int)threadIdx.x >> 6);
    #pragma unroll 2
    for (int it = 0; it < B_ROWS_PER_WAVE; ++it) {
      const int row = wid * B_ROWS_PER_WAVE + it;      // < 67584
      const int g = row * 66 + l * 2;                  // 8B aligned
      floatx2 a = *(const floatx2*)(tpre + g);
      floatx2 c = *(const floatx2*)(in_sp + g);
      floatx2 v = { 0.5f * a.x + c.x, 0.5f * a.y + c.y };
      *(floatx2*)(o_trpre + g) = v;
      if (use_ws) {
        *(uint_t*)(B1 + row * 72 + l * 2) = pk2bf(a.x, a.y);  // 4B dense
        *(uint_t*)(B2 + row * 72 + l * 2) = pk2bf(c.x, c.y);
      }
    }
  }
}

// ---- MFMA kernel: kh-block, 3-kw accumulate, raw-B register shift ----------
// grid (128, 3): x -> (b = x>>3, p0 = (x&7)*8), y = kh. block 256 = 4 waves,
// wave w owns o in [w*32, w*32+32). Per stage (one p-row, k=64):
//   waves 0,1: DMA A (both mats, 128 o) into XOR-swizzled LDS (32 KB)
//   waves 2,3: load raw B row h=p+kh (both mats) -> ds_write padded rows
// LA layout: [o][ks][slot8]x16B, slot = (mat*4+chunk)^(o&7)  (2-way = free)
// LB layout: [i][mat*9+ch9]x16B, row stride 304B              (2-way = free)
__global__ __launch_bounds__(256, 2)
void k_mfma(const ushort_t* __restrict__ A1, const ushort_t* __restrict__ B1,
            float* __restrict__ partials) {
  __shared__ short LA[16384];          // 32 KB
  __shared__ short LB[64 * 152];       // 19 KB (304B rows)

  const int kh = blockIdx.y, bx = blockIdx.x;
  const int b = bx >> 3, p0 = (bx & 7) * 8;
  const int t = threadIdx.x, w = t >> 6, l = t & 63;
  const int quad = l >> 4, l16 = l & 15;

  // A-DMA decode (waves 0,1): chunk c = w*1024 + j*64 + l
  //   o = w*64 + j*4 + (l>>4); g=(l>>3)&1; slot=l&7
  //   stored (mat,c4) = slot ^ (o&7); o&7 = ((j&1)<<2) ^ (l>>4)
  const int lr = l >> 4;
  const int gA = (l >> 3) & 1;
  const int mcE = (l & 7) ^ lr;                        // j even
  const int matE = mcE >> 2, c4E = mcE & 3;
  const long aoffE = (long)matE * 8388608 + (long)(w & 1) * 262144
                   + lr * 4096 + gA * 32 + c4E * 8;
  const long aoffO = aoffE + (matE ? -8388608L : 8388608L);  // j odd: mat flips, c4 same

  const int t2 = t & 127;                              // B-stage thread id

  floatx4 acc[3][2][4] = {};                           // [kw][mt][nt]

  for (int rr = 0; rr < 8; ++rr) {
    const int p = p0 + rr, h = p + kh;
    __syncthreads();                                   // prev compute done
    if (w < 2) {
      const ushort_t* ga = A1 + (long)b * 524288 + p * 64;
      #pragma unroll
      for (int j = 0; j < 16; ++j) {
        const ushort_t* src = ga + ((j & 1) ? aoffO : aoffE) + j * 16384;
        GLDS16(src, LA + (w & 1) * 8192 + j * 512);
      }
    } else {
      const ushort_t* gb = B1 + ((long)b * 4224 + h) * 72;
      #pragma unroll
      for (int k = 0; k < 9; ++k) {
        int c = k * 128 + t2;                          // < 1152
        int i = c / 18, mc = c - i * 18;
        int mat = (mc >= 9) ? 1 : 0, ch9 = mc - mat * 9;
        intx4 v = *(const intx4*)(gb + (long)mat * BRAW + i * 4752 + ch9 * 8);
        *(intx4*)&LB[i * 152 + mat * 72 + ch9 * 8] = v;
      }
    }
    __syncthreads();                                   // staging drained

    #pragma unroll
    for (int ks = 0; ks < 2; ++ks) {
      short8 fa[2][2];                                 // [mat][mt]
      #pragma unroll
      for (int mt = 0; mt < 2; ++mt) {
        const int o = w * 32 + mt * 16 + l16;
        #pragma unroll
        for (int mat = 0; mat < 2; ++mat)
          fa[mat][mt] = *(const short8*)&LA[o * 128 + ks * 64 + (((mat << 2) + quad) ^ (o & 7)) * 8];
      }
      #pragma unroll
      for (int nt = 0; nt < 4; ++nt) {
        const int i = nt * 16 + l16;
        short8 fb[2][3];                               // [mat][kw]
        #pragma unroll
        for (int mat = 0; mat < 2; ++mat) {
          const int base = i * 152 + mat * 72 + ks * 32 + quad * 8;
          intx4 W = *(const intx4*)&LB[base];
          int W4 = *(const int*)&LB[base + 8];
          intx4 f0 = { W.x, W.y, W.z, W.w };
          intx4 f1 = { bsh2(W.y, W.x), bsh2(W.z, W.y), bsh2(W.w, W.z), bsh2(W4, W.w) };
          intx4 f2 = { W.y, W.z, W.w, W4 };
          fb[mat][0] = __builtin_bit_cast(short8, f0);
          fb[mat][1] = __builtin_bit_cast(short8, f1);
          fb[mat][2] = __builtin_bit_cast(short8, f2);
        }
        #pragma unroll
        for (int kw = 0; kw < 3; ++kw)
          #pragma unroll
          for (int mt = 0; mt < 2; ++mt) {
            acc[kw][mt][nt] = __builtin_amdgcn_mfma_f32_16x16x32_bf16(fa[0][mt], fb[0][kw], acc[kw][mt][nt], 0, 0, 0);
            acc[kw][mt][nt] = __builtin_amdgcn_mfma_f32_16x16x32_bf16(fa[1][mt], fb[1][kw], acc[kw][mt][nt], 0, 0, 0);
          }
      }
    }
  }

  // C/D layout: col(i)=lane&15, row(o within 16)=quad*4+reg (HW-verified)
  #pragma unroll
  for (int kw = 0; kw < 3; ++kw) {
    float* slice = partials + (size_t)((kh * 3 + kw) * 128 + bx) * 8192;
    #pragma unroll
    for (int mt = 0; mt < 2; ++mt)
      #pragma unroll
      for (int nt = 0; nt < 4; ++nt)
        #pragma unroll
        for (int rg = 0; rg < 4; ++rg) {
          const int o = w * 32 + mt * 16 + quad * 4 + rg;
          const int i = nt * 16 + l16;
          slice[o * 64 + i] = acc[kw][mt][nt][rg];
        }
  }
}

// ---- split-K reduction + finalize ------------------------------------------
__global__ void k_finalize(const float* __restrict__ partials,
                           const float* __restrict__ weight, float* __restrict__ dw) {
  int tid = blockIdx.x * 256 + threadIdx.x;            // < 73728
  int e = tid >> 13, oi = tid & 8191;
  float s = 0.f;
  #pragma unroll 8
  for (int c = 0; c < 128; ++c) s += partials[(size_t)(e * 128 + c) * 8192 + oi];
  int o = oi >> 6, i = oi & 63;
  int wi = (o * 64 + i) * 9 + e;
  dw[wi] = 0.5f * weight[wi] * s;
}

// ---- fallback (ws too small): slow fp32, zero scratch ----------------------
__global__ void k_naive(const float* __restrict__ out_sp, const float* __restrict__ tpost,
                        const float* __restrict__ tpre, const float* __restrict__ in_sp,
                        const float* __restrict__ weight, float* __restrict__ dw) {
  int tid = blockIdx.x * 256 + threadIdx.x;
  int e = tid >> 13, oi = tid & 8191;
  int o = oi >> 6, i = oi & 63;
  int kh = e / 3, kw = e - kh * 3;
  float acc = 0.f;
  for (int b = 0; b < 16; ++b)
    for (int p = 0; p < 64; ++p) {
      const float* ga = out_sp + ((b * 128 + o) * 64 + p) * 64;
      const float* gn = tpost + ((b * 128 + o) * 64 + p) * 64;
      const float* gb = tpre + ((b * 64 + i) * 66 + p + kh) * 66 + kw;
      const float* gm = in_sp + ((b * 64 + i) * 66 + p + kh) * 66 + kw;
      for (int q = 0; q < 64; ++q) acc += ga[q] * gb[q] - gn[q] * gm[q];
    }
  int wi = (o * 64 + i) * 9 + kh * 3 + kw;
  dw[wi] = 0.5f * weight[wi] * acc;
}

extern "C" void kernel_launch(void* const* d_in, const int* in_sizes, int n_in,
                              void* d_out, int out_size, void* d_ws, size_t ws_size,
                              hipStream_t stream) {
  const float* in_sp  = (const float*)d_in[0];
  const float* out_sp = (const float*)d_in[1];
  const float* tpre   = (const float*)d_in[2];
  const float* tpost  = (const float*)d_in[3];
  const float* weight = (const float*)d_in[4];
  float* out = (float*)d_out;
  float* o_trpre  = out;
  float* o_trpost = out + O_TRPOST;
  float* o_dw     = out + O_DW;

  // ws: A1 | A2 (bf16 16.8MB ea) | B1raw | B2raw (9.7MB ea) | partials 37.7MB
  const size_t WS_NEED = 90767360;
  const int use_mfma = (ws_size >= WS_NEED) ? 1 : 0;
  ushort_t* A1 = (ushort_t*)d_ws;
  ushort_t* A2 = A1 + 8388608;
  ushort_t* B1 = A2 + 8388608;
  ushort_t* B2 = B1 + BRAW;
  float* partials = (float*)(B2 + BRAW);

  k_fill<<<FILL_BLOCKS, 256, 0, stream>>>(in_sp, out_sp, tpre, tpost,
                                          o_trpre, o_trpost, A1, A2, B1, B2, use_mfma);
  if (use_mfma) {
    dim3 g(128, 3);
    k_mfma<<<g, 256, 0, stream>>>(A1, B1, partials);
    k_finalize<<<N_DW / 256, 256, 0, stream>>>(partials, weight, o_dw);
  } else {
    k_naive<<<N_DW / 256, 256, 0, stream>>>(out_sp, tpost, tpre, in_sp, weight, o_dw);
  }
}

// Round 2
// 197.824 us; speedup vs baseline: 1.0655x; 1.0643x over previous
//
#include <hip/hip_runtime.h>

// STDP learner: tr_pre/tr_post elementwise + delta_w = 0.5*w*(conv-wgrad pair).
// delta_w[o,i,kh,kw] = 0.5*w[o,i,kh,kw] *
//   sum_{b,p,q} tpre[b,i,p+kh,q+kw]*out[b,o,p,q] - tpost[b,o,p,q]*in[b,i,p+kh,q+kw]
// Sizes: B=16 CIN=64 H=W=66 COUT=128 HO=WO=64 KH=KW=3
// out layout: [tr_pre 4460544][tr_post 8388608][delta_w 73728]
//
// R7: kill the staging pipeline (R6 post-mortem: k_fill's 2.5 TB/s is the
// stream-mix ceiling, not instruction density; only deleting bytes helps).
//  - No A1/A2/B1/B2 staging mats. MFMA role reads raw fp32 inputs directly,
//    converts bf16 via v_cvt_pk_bf16_f32 (HW RNE == old f2bf, bit-identical).
//  - A operand: direct global->reg (no LDS; o is wave-partitioned so there is
//    no cross-wave reuse). Loads issued at stage top, consumed after B stage.
//  - B operand: fp32 row -> cvt -> LDS, double-buffered => 1 barrier/stage.
//  - fill (pure elementwise now, 154MB) MERGED into the same kernel as extra
//    blocks: zero dependency on mfma role => HBM streaming overlaps MFMA/L3
//    compute. mfma blocks first in grid (longest-first packing).
//  - partials + k_finalize epilogue unchanged (R4 showed atomics 7.6x worse).

typedef unsigned short ushort_t;
typedef unsigned int uint_t;
typedef __attribute__((ext_vector_type(8))) short short8;
typedef __attribute__((ext_vector_type(4))) float floatx4;
typedef __attribute__((ext_vector_type(2))) float floatx2;
typedef __attribute__((ext_vector_type(4))) int intx4;
typedef __attribute__((ext_vector_type(4))) uint_t uintx4;

#define N_POST   8388608     // 16*128*64*64
#define N_DW     73728       // 128*64*9
#define O_TRPOST 4460544
#define O_DW     12849152

#define MFMA_BLOCKS  384     // 3 kh * 128 (b,p0)
#define FILLA_BLOCKS 1024
#define FILLB_BLOCKS 768
#define TOTAL_BLOCKS 2176
#define B_ROWS_PER_WAVE 22   // 768*4*22 = 67584 rows exactly

// packed fp32->bf16, HW RNE (same rounding as old bit-twiddle f2bf)
__device__ __forceinline__ uint_t cvt2bf(float lo, float hi) {
  uint_t r; asm("v_cvt_pk_bf16_f32 %0, %1, %2" : "=v"(r) : "v"(lo), "v"(hi)); return r;
}
__device__ __forceinline__ uint_t cvt2bfn(float lo, float hi) {   // negated (free VOP3 mods)
  uint_t r; asm("v_cvt_pk_bf16_f32 %0, -%1, -%2" : "=v"(r) : "v"(lo), "v"(hi)); return r;
}
// bytes [2..5] of (hi:lo) -- one v_alignbit_b32
__device__ __forceinline__ int bsh2(int hi, int lo) {
  return (int)((((unsigned long long)(uint_t)hi << 32) | (uint_t)lo) >> 16);
}

// ---- merged kernel ---------------------------------------------------------
// bx < 384:        MFMA role (needs ws for partials)
// 384..1408:       elementwise tr_post (float4 grid-stride, 8 iters exact)
// 1408..2176:      elementwise tr_pre (wave-per-row, lanes 0..32 x float2)
__global__ __launch_bounds__(256, 2)
void k_main(const float* __restrict__ in_sp, const float* __restrict__ out_sp,
            const float* __restrict__ tpre, const float* __restrict__ tpost,
            float* __restrict__ o_trpre, float* __restrict__ o_trpost,
            float* __restrict__ partials, int use_ws) {
  const int bx0 = blockIdx.x;
  const int t = threadIdx.x;

  if (bx0 >= MFMA_BLOCKS) {
    if (bx0 < MFMA_BLOCKS + FILLA_BLOCKS) {
      int i4 = (bx0 - MFMA_BLOCKS) * 256 + t;          // 2097152 = 262144*8
      #pragma unroll
      for (int it = 0; it < 8; ++it, i4 += FILLA_BLOCKS * 256) {
        floatx4 o = *(const floatx4*)(out_sp + i4 * 4);
        floatx4 p = *(const floatx4*)(tpost + i4 * 4);
        *(floatx4*)(o_trpost + i4 * 4) = 0.5f * p + o;
      }
    } else {
      const int l = t & 63;
      if (l >= 33) return;
      const int wid = (bx0 - (MFMA_BLOCKS + FILLA_BLOCKS)) * 4 + (t >> 6);
      #pragma unroll 2
      for (int it = 0; it < B_ROWS_PER_WAVE; ++it) {
        const int g = (wid * B_ROWS_PER_WAVE + it) * 66 + l * 2;
        floatx2 a = *(const floatx2*)(tpre + g);
        floatx2 c = *(const floatx2*)(in_sp + g);
        floatx2 v = { 0.5f * a.x + c.x, 0.5f * a.y + c.y };
        *(floatx2*)(o_trpre + g) = v;
      }
    }
    return;
  }
  if (!use_ws) return;                                 // fallback handles dw

  // ---- MFMA role: grid x -> kh = bx0>>7, bx = bx0&127 -> b = bx>>3, p0
  // block 256 = 4 waves, wave w owns o in [w*32, w*32+32). Per stage (p-row):
  //   A (out, tpost): 16x float4 global->reg, cvt at use. No LDS, no reuse.
  //   B (tpre, in): 64 i-rows x 66 fp32 -> cvt -> LDS, double-buffered.
  // LB layout: [buf][i][mat*72 + e] shorts, row stride 304B (2-way banks=free)
  __shared__ short LB[2][9728];                        // 38 KB
  const int kh = bx0 >> 7, bx = bx0 & 127;
  const int b = bx >> 3, p0 = (bx & 7) * 8;
  const int w = t >> 6, l = t & 63;
  const int quad = l >> 4, l16 = l & 15;
  const int si = t >> 2, sg = t & 3;                   // B-stage: i row, 16-col seg

  const float* arow0 = out_sp + ((b * 128 + w * 32 + l16) * 4096 + quad * 8 + p0 * 64);
  const float* arow1 = tpost  + ((b * 128 + w * 32 + l16) * 4096 + quad * 8 + p0 * 64);
  const float* brow0 = tpre  + ((b * 64 + si) * 66 * 66 + sg * 16);
  const float* brow1 = in_sp + ((b * 64 + si) * 66 * 66 + sg * 16);
  short* Lrow = &LB[0][0] + si * 152 + sg * 16;        // + buf*9728 + mat*72

  floatx4 acc[3][2][4] = {};                           // [kw][mt][nt]

  auto stageB = [&](int h, int buf) {
    const float* r0 = brow0 + h * 66;
    const float* r1 = brow1 + h * 66;
    floatx2 v0[8], v1[8];
    #pragma unroll
    for (int k = 0; k < 8; ++k) {                      // rows only 8B-aligned
      v0[k] = *(const floatx2*)(r0 + 2 * k);
      v1[k] = *(const floatx2*)(r1 + 2 * k);
    }
    uintx4 u0a = { cvt2bf(v0[0].x, v0[0].y), cvt2bf(v0[1].x, v0[1].y),
                   cvt2bf(v0[2].x, v0[2].y), cvt2bf(v0[3].x, v0[3].y) };
    uintx4 u0b = { cvt2bf(v0[4].x, v0[4].y), cvt2bf(v0[5].x, v0[5].y),
                   cvt2bf(v0[6].x, v0[6].y), cvt2bf(v0[7].x, v0[7].y) };
    uintx4 u1a = { cvt2bf(v1[0].x, v1[0].y), cvt2bf(v1[1].x, v1[1].y),
                   cvt2bf(v1[2].x, v1[2].y), cvt2bf(v1[3].x, v1[3].y) };
    uintx4 u1b = { cvt2bf(v1[4].x, v1[4].y), cvt2bf(v1[5].x, v1[5].y),
                   cvt2bf(v1[6].x, v1[6].y), cvt2bf(v1[7].x, v1[7].y) };
    short* Lb = Lrow + buf * 9728;
    *(uintx4*)(Lb)      = u0a;                         // mat0 = tpre
    *(uintx4*)(Lb + 8)  = u0b;
    *(uintx4*)(Lb + 72) = u1a;                         // mat1 = in
    *(uintx4*)(Lb + 80) = u1b;
    if (sg == 3) {                                     // elems 64,65
      floatx2 t0 = *(const floatx2*)(r0 + 16);
      floatx2 t1 = *(const floatx2*)(r1 + 16);
      *(uint_t*)(Lb + 16) = cvt2bf(t0.x, t0.y);
      *(uint_t*)(Lb + 88) = cvt2bf(t1.x, t1.y);
    }
  };

  stageB(p0 + kh, 0);
  __syncthreads();

  for (int rr = 0; rr < 8; ++rr) {
    // A loads for this stage (issued first; latency hides under B staging)
    floatx4 ar[2][2][2][2];                            // [mat][mt][ks][half]
    #pragma unroll
    for (int mt = 0; mt < 2; ++mt)
      #pragma unroll
      for (int ks = 0; ks < 2; ++ks)
        #pragma unroll
        for (int hf = 0; hf < 2; ++hf) {
          const int off = rr * 64 + mt * 65536 + ks * 32 + hf * 4;
          ar[0][mt][ks][hf] = *(const floatx4*)(arow0 + off);
          ar[1][mt][ks][hf] = *(const floatx4*)(arow1 + off);
        }
    if (rr < 7) stageB(p0 + rr + 1 + kh, (rr + 1) & 1);

    const short* Lbb = &LB[0][0] + (rr & 1) * 9728;
    #pragma unroll
    for (int ks = 0; ks < 2; ++ks) {
      short8 fa[2][2];                                 // [mat][mt]
      #pragma unroll
      for (int mt = 0; mt < 2; ++mt) {
        uintx4 ua = { cvt2bf (ar[0][mt][ks][0].x, ar[0][mt][ks][0].y),
                      cvt2bf (ar[0][mt][ks][0].z, ar[0][mt][ks][0].w),
                      cvt2bf (ar[0][mt][ks][1].x, ar[0][mt][ks][1].y),
                      cvt2bf (ar[0][mt][ks][1].z, ar[0][mt][ks][1].w) };
        uintx4 un = { cvt2bfn(ar[1][mt][ks][0].x, ar[1][mt][ks][0].y),
                      cvt2bfn(ar[1][mt][ks][0].z, ar[1][mt][ks][0].w),
                      cvt2bfn(ar[1][mt][ks][1].x, ar[1][mt][ks][1].y),
                      cvt2bfn(ar[1][mt][ks][1].z, ar[1][mt][ks][1].w) };
        fa[0][mt] = __builtin_bit_cast(short8, ua);    // A1 = out
        fa[1][mt] = __builtin_bit_cast(short8, un);    // A2 = -tpost
      }
      #pragma unroll
      for (int nt = 0; nt < 4; ++nt) {
        const int i = nt * 16 + l16;
        short8 fb[2][3];                               // [mat][kw]
        #pragma unroll
        for (int mat = 0; mat < 2; ++mat) {
          const int base = i * 152 + mat * 72 + ks * 32 + quad * 8;
          intx4 W = *(const intx4*)&Lbb[base];
          int W4 = *(const int*)&Lbb[base + 8];
          intx4 f0 = { W.x, W.y, W.z, W.w };
          intx4 f1 = { bsh2(W.y, W.x), bsh2(W.z, W.y), bsh2(W.w, W.z), bsh2(W4, W.w) };
          intx4 f2 = { W.y, W.z, W.w, W4 };
          fb[mat][0] = __builtin_bit_cast(short8, f0);
          fb[mat][1] = __builtin_bit_cast(short8, f1);
          fb[mat][2] = __builtin_bit_cast(short8, f2);
        }
        #pragma unroll
        for (int kw = 0; kw < 3; ++kw)
          #pragma unroll
          for (int mt = 0; mt < 2; ++mt) {
            acc[kw][mt][nt] = __builtin_amdgcn_mfma_f32_16x16x32_bf16(fa[0][mt], fb[0][kw], acc[kw][mt][nt], 0, 0, 0);
            acc[kw][mt][nt] = __builtin_amdgcn_mfma_f32_16x16x32_bf16(fa[1][mt], fb[1][kw], acc[kw][mt][nt], 0, 0, 0);
          }
      }
    }
    __syncthreads();                                   // buf reuse fence
  }

  // C/D layout: col(i)=lane&15, row(o within 16)=quad*4+reg (HW-verified)
  #pragma unroll
  for (int kw = 0; kw < 3; ++kw) {
    float* slice = partials + (size_t)((kh * 3 + kw) * 128 + bx) * 8192;
    #pragma unroll
    for (int mt = 0; mt < 2; ++mt)
      #pragma unroll
      for (int nt = 0; nt < 4; ++nt)
        #pragma unroll
        for (int rg = 0; rg < 4; ++rg) {
          const int o = w * 32 + mt * 16 + quad * 4 + rg;
          const int i = nt * 16 + l16;
          slice[o * 64 + i] = acc[kw][mt][nt][rg];
        }
  }
}

// ---- split-K reduction + finalize ------------------------------------------
__global__ void k_finalize(const float* __restrict__ partials,
                           const float* __restrict__ weight, float* __restrict__ dw) {
  int tid = blockIdx.x * 256 + threadIdx.x;            // < 73728
  int e = tid >> 13, oi = tid & 8191;
  float s = 0.f;
  #pragma unroll 8
  for (int c = 0; c < 128; ++c) s += partials[(size_t)(e * 128 + c) * 8192 + oi];
  int o = oi >> 6, i = oi & 63;
  int wi = (o * 64 + i) * 9 + e;
  dw[wi] = 0.5f * weight[wi] * s;
}

// ---- fallback (ws too small): slow fp32, zero scratch ----------------------
__global__ void k_naive(const float* __restrict__ out_sp, const float* __restrict__ tpost,
                        const float* __restrict__ tpre, const float* __restrict__ in_sp,
                        const float* __restrict__ weight, float* __restrict__ dw) {
  int tid = blockIdx.x * 256 + threadIdx.x;
  int e = tid >> 13, oi = tid & 8191;
  int o = oi >> 6, i = oi & 63;
  int kh = e / 3, kw = e - kh * 3;
  float acc = 0.f;
  for (int b = 0; b < 16; ++b)
    for (int p = 0; p < 64; ++p) {
      const float* ga = out_sp + ((b * 128 + o) * 64 + p) * 64;
      const float* gn = tpost + ((b * 128 + o) * 64 + p) * 64;
      const float* gb = tpre + ((b * 64 + i) * 66 + p + kh) * 66 + kw;
      const float* gm = in_sp + ((b * 64 + i) * 66 + p + kh) * 66 + kw;
      for (int q = 0; q < 64; ++q) acc += ga[q] * gb[q] - gn[q] * gm[q];
    }
  int wi = (o * 64 + i) * 9 + kh * 3 + kw;
  dw[wi] = 0.5f * weight[wi] * acc;
}

extern "C" void kernel_launch(void* const* d_in, const int* in_sizes, int n_in,
                              void* d_out, int out_size, void* d_ws, size_t ws_size,
                              hipStream_t stream) {
  const float* in_sp  = (const float*)d_in[0];
  const float* out_sp = (const float*)d_in[1];
  const float* tpre   = (const float*)d_in[2];
  const float* tpost  = (const float*)d_in[3];
  const float* weight = (const float*)d_in[4];
  float* out = (float*)d_out;
  float* o_trpre  = out;
  float* o_trpost = out + O_TRPOST;
  float* o_dw     = out + O_DW;

  // ws: partials only now (9*128*8192 fp32 = 37.7MB)
  const size_t WS_NEED = (size_t)9 * 128 * 8192 * 4;
  const int use_mfma = (ws_size >= WS_NEED) ? 1 : 0;
  float* partials = (float*)d_ws;

  k_main<<<TOTAL_BLOCKS, 256, 0, stream>>>(in_sp, out_sp, tpre, tpost,
                                           o_trpre, o_trpost, partials, use_mfma);
  if (use_mfma) {
    k_finalize<<<N_DW / 256, 256, 0, stream>>>(partials, weight, o_dw);
  } else {
    k_naive<<<N_DW / 256, 256, 0, stream>>>(out_sp, tpost, tpre, in_sp, weight, o_dw);
  }
}